// Round 9
// baseline (346.700 us; speedup 1.0000x reference)
//
#include <hip/hip_runtime.h>
#include <math.h>

// Shapes (fixed by the reference)
constexpr int Bn  = 16;
constexpr int Sn  = 512;
constexpr int S2n = 64;
constexpr int Hn  = 128;
constexpr int Ln  = 3;

#define TID ((int)threadIdx.x)

__device__ inline float wave_reduce_sum(float v) {
#pragma unroll
  for (int off = 32; off > 0; off >>= 1) v += __shfl_xor(v, off, 64);
  return v;
}

__device__ inline float block_reduce_sum(float v, float* red) {
  v = wave_reduce_sum(v);
  int w  = TID >> 6;
  int nw = (int)blockDim.x >> 6;
  if ((TID & 63) == 0) red[w] = v;
  __syncthreads();
  float s = 0.f;
  for (int i = 0; i < nw; ++i) s += red[i];
  __syncthreads();
  return s;
}

__device__ inline float sigm(float x) { return 1.f / (1.f + expf(-x)); }

// All weight transposes in ONE dispatch. dst[k][n] = src[n*stride + k].
__global__ __launch_bounds__(256) void transpose_all(
    const float* __restrict__ Wn, const float* __restrict__ Wu,
    const float* __restrict__ Wr, const float* __restrict__ Wt,
    const float* __restrict__ Wa1,
    float* __restrict__ WnT, float* __restrict__ WuT,
    float* __restrict__ WrT, float* __restrict__ WtT,
    float* __restrict__ Wa1T)
{
  const float* src; float* dst; int K, stride;
  switch (blockIdx.z) {
    case 0:  src = Wn;  dst = WnT;  K = 128; stride = 128; break;
    case 1:  src = Wu;  dst = WuT;  K = 256; stride = 256; break;
    case 2:  src = Wr;  dst = WrT;  K = 256; stride = 256; break;
    case 3:  src = Wt;  dst = WtT;  K = 256; stride = 256; break;
    default: src = Wa1; dst = Wa1T; K = 256; stride = 256; break;
  }
  int k0 = blockIdx.x * 32;
  if (k0 >= K) return;
  int n0 = blockIdx.y * 32;
  __shared__ float t[32][33];
  int tx = TID & 31, ty = TID >> 5;
#pragma unroll
  for (int i = 0; i < 32; i += 8)
    t[ty + i][tx] = src[(size_t)(n0 + ty + i) * stride + k0 + tx];
  __syncthreads();
#pragma unroll
  for (int i = 0; i < 32; i += 8)
    dst[(size_t)(k0 + ty + i) * 128 + n0 + tx] = t[tx][ty + i];
}

// Y[M,128] = X[M,K] @ WT[K,128] (+bias). 16 rows/block, 4r x 2c per thread.
__global__ __launch_bounds__(256) void gemm_wt(
    const float* __restrict__ X, const float* __restrict__ WT,
    const float* __restrict__ bias, float* __restrict__ Y,
    int M, int K)
{
  extern __shared__ float Xs[];              // [16][K]
  int r0 = blockIdx.x * 16;
  const float* xsrc = X + (size_t)r0 * K;
  int tot4 = (16 * K) >> 2;
  for (int i = TID; i < tot4; i += 256)
    ((float4*)Xs)[i] = ((const float4*)xsrc)[i];
  __syncthreads();

  int cg = (TID & 63) * 2;
  int rb = (TID >> 6) * 4;
  float acc[4][2] = {};

#pragma unroll 4
  for (int k = 0; k < K; k += 4) {
    const float* wk = WT + (size_t)k * 128 + cg;
    float2 w0 = *(const float2*)(wk);
    float2 w1 = *(const float2*)(wk + 128);
    float2 w2 = *(const float2*)(wk + 256);
    float2 w3 = *(const float2*)(wk + 384);
#pragma unroll
    for (int i = 0; i < 4; ++i) {
      float4 x = *(const float4*)&Xs[(rb + i) * K + k];
      acc[i][0] = fmaf(x.x, w0.x, acc[i][0]);
      acc[i][0] = fmaf(x.y, w1.x, acc[i][0]);
      acc[i][0] = fmaf(x.z, w2.x, acc[i][0]);
      acc[i][0] = fmaf(x.w, w3.x, acc[i][0]);
      acc[i][1] = fmaf(x.x, w0.y, acc[i][1]);
      acc[i][1] = fmaf(x.y, w1.y, acc[i][1]);
      acc[i][1] = fmaf(x.z, w2.y, acc[i][1]);
      acc[i][1] = fmaf(x.w, w3.y, acc[i][1]);
    }
  }

  float2 bv = {0.f, 0.f};
  if (bias) bv = *(const float2*)(bias + cg);
#pragma unroll
  for (int i = 0; i < 4; ++i) {
    float2 v = {acc[i][0] + bv.x, acc[i][1] + bv.y};
    *(float2*)(Y + (size_t)(r0 + rb + i) * 128 + cg) = v;
  }
}

// Fused gate gemms: z = sigmoid(a@Wu^T+bu), rh = sigmoid(a@Wr^T+br)*h.
__global__ __launch_bounds__(256) void gemm_zr(
    const float* __restrict__ A, const float* __restrict__ WuT,
    const float* __restrict__ WrT, const float* __restrict__ bu,
    const float* __restrict__ br, const float* __restrict__ h,
    float* __restrict__ z, float* __restrict__ rh)
{
  __shared__ float Xs[16 * 256];
  int r0 = blockIdx.x * 16;
  const float* xsrc = A + (size_t)r0 * 256;
  for (int i = TID; i < 1024; i += 256)
    ((float4*)Xs)[i] = ((const float4*)xsrc)[i];
  __syncthreads();

  int cg = (TID & 63) * 2;
  int rb = (TID >> 6) * 4;
  float aU[4][2] = {}, aR[4][2] = {};

#pragma unroll 4
  for (int k = 0; k < 256; k += 4) {
    const float* wu = WuT + (size_t)k * 128 + cg;
    const float* wr = WrT + (size_t)k * 128 + cg;
    float2 u0 = *(const float2*)(wu);
    float2 u1 = *(const float2*)(wu + 128);
    float2 u2 = *(const float2*)(wu + 256);
    float2 u3 = *(const float2*)(wu + 384);
    float2 q0 = *(const float2*)(wr);
    float2 q1 = *(const float2*)(wr + 128);
    float2 q2 = *(const float2*)(wr + 256);
    float2 q3 = *(const float2*)(wr + 384);
#pragma unroll
    for (int i = 0; i < 4; ++i) {
      float4 x = *(const float4*)&Xs[(rb + i) * 256 + k];
      aU[i][0] = fmaf(x.x, u0.x, aU[i][0]);
      aU[i][0] = fmaf(x.y, u1.x, aU[i][0]);
      aU[i][0] = fmaf(x.z, u2.x, aU[i][0]);
      aU[i][0] = fmaf(x.w, u3.x, aU[i][0]);
      aU[i][1] = fmaf(x.x, u0.y, aU[i][1]);
      aU[i][1] = fmaf(x.y, u1.y, aU[i][1]);
      aU[i][1] = fmaf(x.z, u2.y, aU[i][1]);
      aU[i][1] = fmaf(x.w, u3.y, aU[i][1]);
      aR[i][0] = fmaf(x.x, q0.x, aR[i][0]);
      aR[i][0] = fmaf(x.y, q1.x, aR[i][0]);
      aR[i][0] = fmaf(x.z, q2.x, aR[i][0]);
      aR[i][0] = fmaf(x.w, q3.x, aR[i][0]);
      aR[i][1] = fmaf(x.x, q0.y, aR[i][1]);
      aR[i][1] = fmaf(x.y, q1.y, aR[i][1]);
      aR[i][1] = fmaf(x.z, q2.y, aR[i][1]);
      aR[i][1] = fmaf(x.w, q3.y, aR[i][1]);
    }
  }

  float2 buv = *(const float2*)(bu + cg);
  float2 brv = *(const float2*)(br + cg);
#pragma unroll
  for (int i = 0; i < 4; ++i) {
    size_t row = r0 + rb + i;
    float2 hv = *(const float2*)(h + row * 128 + cg);
    float2 zv = {sigm(aU[i][0] + buv.x), sigm(aU[i][1] + buv.y)};
    float2 rv = {sigm(aR[i][0] + brv.x) * hv.x,
                 sigm(aR[i][1] + brv.y) * hv.y};
    *(float2*)(z  + row * 128 + cg) = zv;
    *(float2*)(rh + row * 128 + cg) = rv;
  }
}

// Fused candidate gemm + gate combine + row-local epilogue gemm:
// hnew = h_in + z*(tanh([p|rh]@WtT + bt) - h_in); h_out = hnew;
// e_out = hnew @ WeT (+be)   (p for next step, or kp on the last step)
__global__ __launch_bounds__(256) void gemm_hp(
    const float* __restrict__ p, const float* __restrict__ rh,
    const float* __restrict__ WtT, const float* __restrict__ bt,
    const float* __restrict__ z, const float* __restrict__ h_in,
    float* __restrict__ h_out,
    const float* __restrict__ WeT, const float* __restrict__ be,
    float* __restrict__ e_out)
{
  __shared__ float Xs[16 * 256];
  int r0 = blockIdx.x * 16;
  const float* psrc = p  + (size_t)r0 * 128;
  const float* rsrc = rh + (size_t)r0 * 128;
  for (int i = TID; i < 512; i += 256) {
    int row = i >> 5, g = i & 31;
    *(float4*)&Xs[row * 256 + 4 * g] =
        ((const float4*)(psrc + (size_t)row * 128))[g];
    *(float4*)&Xs[row * 256 + 128 + 4 * g] =
        ((const float4*)(rsrc + (size_t)row * 128))[g];
  }
  __syncthreads();

  int cg = (TID & 63) * 2;
  int rb = (TID >> 6) * 4;
  float acc[4][2] = {};

#pragma unroll 4
  for (int k = 0; k < 256; k += 4) {
    const float* wk = WtT + (size_t)k * 128 + cg;
    float2 w0 = *(const float2*)(wk);
    float2 w1 = *(const float2*)(wk + 128);
    float2 w2 = *(const float2*)(wk + 256);
    float2 w3 = *(const float2*)(wk + 384);
#pragma unroll
    for (int i = 0; i < 4; ++i) {
      float4 x = *(const float4*)&Xs[(rb + i) * 256 + k];
      acc[i][0] = fmaf(x.x, w0.x, acc[i][0]);
      acc[i][0] = fmaf(x.y, w1.x, acc[i][0]);
      acc[i][0] = fmaf(x.z, w2.x, acc[i][0]);
      acc[i][0] = fmaf(x.w, w3.x, acc[i][0]);
      acc[i][1] = fmaf(x.x, w0.y, acc[i][1]);
      acc[i][1] = fmaf(x.y, w1.y, acc[i][1]);
      acc[i][1] = fmaf(x.z, w2.y, acc[i][1]);
      acc[i][1] = fmaf(x.w, w3.y, acc[i][1]);
    }
  }

  float2 btv = *(const float2*)(bt + cg);
  float hn[4][2];
#pragma unroll
  for (int i = 0; i < 4; ++i) {
    size_t row = r0 + rb + i;
    float2 hv = *(const float2*)(h_in + row * 128 + cg);
    float2 zv = *(const float2*)(z + row * 128 + cg);
    hn[i][0] = hv.x + zv.x * (tanhf(acc[i][0] + btv.x) - hv.x);
    hn[i][1] = hv.y + zv.y * (tanhf(acc[i][1] + btv.y) - hv.y);
    float2 o = {hn[i][0], hn[i][1]};
    *(float2*)(h_out + row * 128 + cg) = o;
  }

  // Row-local epilogue gemm on hnew (bounce hnew through LDS).
  __syncthreads();                       // main-loop Xs reads done
#pragma unroll
  for (int i = 0; i < 4; ++i) {
    Xs[(rb + i) * 128 + cg]     = hn[i][0];
    Xs[(rb + i) * 128 + cg + 1] = hn[i][1];
  }
  __syncthreads();

  float acc2[4][2] = {};
#pragma unroll 4
  for (int k = 0; k < 128; k += 4) {
    const float* wk = WeT + (size_t)k * 128 + cg;
    float2 w0 = *(const float2*)(wk);
    float2 w1 = *(const float2*)(wk + 128);
    float2 w2 = *(const float2*)(wk + 256);
    float2 w3 = *(const float2*)(wk + 384);
#pragma unroll
    for (int i = 0; i < 4; ++i) {
      float4 x = *(const float4*)&Xs[(rb + i) * 128 + k];
      acc2[i][0] = fmaf(x.x, w0.x, acc2[i][0]);
      acc2[i][0] = fmaf(x.y, w1.x, acc2[i][0]);
      acc2[i][0] = fmaf(x.z, w2.x, acc2[i][0]);
      acc2[i][0] = fmaf(x.w, w3.x, acc2[i][0]);
      acc2[i][1] = fmaf(x.x, w0.y, acc2[i][1]);
      acc2[i][1] = fmaf(x.y, w1.y, acc2[i][1]);
      acc2[i][1] = fmaf(x.z, w2.y, acc2[i][1]);
      acc2[i][1] = fmaf(x.w, w3.y, acc2[i][1]);
    }
  }
  float2 bev = {0.f, 0.f};
  if (be) bev = *(const float2*)(be + cg);
#pragma unroll
  for (int i = 0; i < 4; ++i) {
    float2 v = {acc2[i][0] + bev.x, acc2[i][1] + bev.y};
    *(float2*)(e_out + (size_t)(r0 + rb + i) * 128 + cg) = v;
  }
}

// a[b,i,c] = sum_j adj[b,i,j] * cat(p,h)[b,j,c]  (ballot-compacted sparse)
__global__ __launch_bounds__(256) void adj_mm_sparse(
    const float* __restrict__ adj, const float* __restrict__ p,
    const float* __restrict__ h, float* __restrict__ a)
{
  int wid = TID >> 6, lane = TID & 63;
  int b = blockIdx.y;
  int i = blockIdx.x * 4 + wid;

  const float* xbase = (lane < 32)
      ? (p + (size_t)b * Sn * Hn + 4 * lane)
      : (h + (size_t)b * Sn * Hn + 4 * (lane - 32));
  const float* arow = adj + ((size_t)b * Sn + i) * Sn;

  float4 acc = {0.f, 0.f, 0.f, 0.f};
  for (int j0 = 0; j0 < Sn; j0 += 64) {
    float av = arow[j0 + lane];
    unsigned long long mask = __ballot(av != 0.f);
    while (mask) {
      int jj = __ffsll((unsigned long long)mask) - 1;
      mask &= mask - 1;
      float w = __shfl(av, jj, 64);
      float4 x = *(const float4*)(xbase + (size_t)(j0 + jj) * Hn);
      acc.x = fmaf(w, x.x, acc.x);
      acc.y = fmaf(w, x.y, acc.y);
      acc.z = fmaf(w, x.z, acc.z);
      acc.w = fmaf(w, x.w, acc.w);
    }
  }
  int c = (lane < 32) ? 4 * lane : 128 + 4 * (lane - 32);
  *(float4*)(a + ((size_t)b * Sn + i) * (2 * Hn) + c) = acc;
}

// E[b,q,k] = mask ? exp(relu(Wa2 . relu(qp[b,q]+kp[b,k]+ba1) + ba2)) : 0
__global__ __launch_bounds__(256) void scores_exp_v2(
    const float* __restrict__ qp, const float* __restrict__ kp,
    const float* __restrict__ ba1, const float* __restrict__ Wa2,
    const float* __restrict__ ba2, const float* __restrict__ am,
    const float* __restrict__ sm, float* __restrict__ E)
{
  constexpr int KT = 32;
  __shared__ float qs[64][132];
  __shared__ float ks[KT][132];
  __shared__ float w2s[128];
  __shared__ float es[64][33];

  int b = blockIdx.y, kt = blockIdx.x * KT;

  const float* qsrc = qp + (size_t)b * S2n * Hn;
  for (int f = TID; f < 64 * 32; f += 256) {
    int q = f >> 5, g = f & 31;
    float4 v  = ((const float4*)qsrc)[f];
    float4 bb = ((const float4*)ba1)[g];
    v.x += bb.x; v.y += bb.y; v.z += bb.z; v.w += bb.w;
    *(float4*)&qs[q][4 * g] = v;
  }
  const float* ksrc = kp + ((size_t)b * Sn + kt) * Hn;
  for (int f = TID; f < KT * 32; f += 256) {
    int k = f >> 5, g = f & 31;
    *(float4*)&ks[k][4 * g] = ((const float4*)ksrc)[f];
  }
  if (TID < 128) w2s[TID] = Wa2[TID];
  __syncthreads();

  const int q0 = (TID & 15) * 4;
  const int k0 = (TID >> 4) * 2;
  float acc[4][2] = {};

#pragma unroll 4
  for (int h = 0; h < 128; ++h) {
    float w  = w2s[h];
    float kv0 = ks[k0][h], kv1 = ks[k0 + 1][h];
#pragma unroll
    for (int i = 0; i < 4; ++i) {
      float qv = qs[q0 + i][h];
      acc[i][0] = fmaf(fmaxf(qv + kv0, 0.f), w, acc[i][0]);
      acc[i][1] = fmaf(fmaxf(qv + kv1, 0.f), w, acc[i][1]);
    }
  }

  float b2 = ba2[0];
#pragma unroll
  for (int i = 0; i < 4; ++i) {
    float amq = am[b * S2n + q0 + i];
#pragma unroll
    for (int j = 0; j < 2; ++j) {
      float m = amq * sm[b * Sn + kt + k0 + j];
      float s = fmaxf(acc[i][j] + b2, 0.f);
      es[q0 + i][k0 + j] = (m > 0.f) ? expf(s) : 0.f;
    }
  }
  __syncthreads();

  float* Eb = E + ((size_t)b * S2n) * Sn + kt;
  for (int f = TID; f < 64 * KT; f += 256) {
    int q = f >> 5, kin = f & 31;
    Eb[(size_t)q * Sn + kin] = es[q][kin];
  }
}

// sf[b,q,:] = (1/max(sum_k E,2e-15)) * sum_k E[b,q,k]*out[b,k,:]
__global__ __launch_bounds__(128) void attn_sf(
    const float* __restrict__ E, const float* __restrict__ out,
    float* __restrict__ sf)
{
  __shared__ float Es[512];
  __shared__ float red[2];
  int b = blockIdx.y, q = blockIdx.x, t = TID;
  const float* Erow = E + ((size_t)b * S2n + q) * Sn;
  for (int i = t; i < Sn; i += 128) Es[i] = Erow[i];
  __syncthreads();
  float part = Es[t] + Es[t + 128] + Es[t + 256] + Es[t + 384];
  part = wave_reduce_sum(part);
  if ((t & 63) == 0) red[t >> 6] = part;
  __syncthreads();
  float scale = 1.f / fmaxf(red[0] + red[1], 2e-15f);

  const float* ob = out + (size_t)b * Sn * Hn + t;
  float acc = 0.f;
#pragma unroll 8
  for (int k = 0; k < Sn; ++k) acc = fmaf(Es[k], ob[(size_t)k * Hn], acc);
  sf[((size_t)b * S2n + q) * Hn + t] = acc * scale;
}

// adv[b,s,l] = sum_h actions[b,s,h] * (weight[l] @ sf[b,s])_h + bias[l]
__global__ __launch_bounds__(128) void adv_kernel(
    const float* __restrict__ actions, const float* __restrict__ sf,
    const float* __restrict__ weight, const float* __restrict__ bias,
    float* __restrict__ adv)
{
  __shared__ float acts[128], sfs[128];
  __shared__ float red[2];
  int b = blockIdx.y, s = blockIdx.x, t = TID;
  size_t row = (size_t)b * S2n + s;
  acts[t] = actions[row * Hn + t];
  sfs[t]  = sf[row * Hn + t];
  __syncthreads();
  for (int l = 0; l < Ln; ++l) {
    const float* wr = weight + ((size_t)l * Hn + t) * Hn;
    float tmp = 0.f;
#pragma unroll 4
    for (int k = 0; k < Hn; k += 4) {
      float4 wv = *(const float4*)(wr + k);
      tmp = fmaf(wv.x, sfs[k],     tmp);
      tmp = fmaf(wv.y, sfs[k + 1], tmp);
      tmp = fmaf(wv.z, sfs[k + 2], tmp);
      tmp = fmaf(wv.w, sfs[k + 3], tmp);
    }
    float pa  = acts[t] * tmp;
    float tot = block_reduce_sum(pa, red);
    if (t == 0) adv[row * Ln + l] = tot + bias[l];
  }
}

// Fused: sem = mean_q sf ; val = Wv.sem+bv ; q = val + adv - mean(adv)
__global__ __launch_bounds__(256) void final2_kernel(
    const float* __restrict__ sf, const float* __restrict__ am,
    const float* __restrict__ Wv, const float* __restrict__ bv,
    const float* __restrict__ adv, float* __restrict__ outq)
{
  __shared__ float red[4];
  int b = blockIdx.x, t = TID;
  float num = 0.f;
  for (int i = 0; i < S2n; ++i) num += am[b * S2n + i];
  float pv = 0.f;
  if (t < Hn) {
    float s = 0.f;
    const float* sb = sf + (size_t)b * S2n * Hn + t;
    for (int q = 0; q < S2n; ++q) s += sb[(size_t)q * Hn];
    pv = Wv[t] * (s / num);
  }
  float val = block_reduce_sum(pv, red) + bv[0];
  const float* advb = adv + (size_t)b * S2n * Ln;
  float pa   = (t < S2n * Ln) ? advb[t] : 0.f;
  float mean = block_reduce_sum(pa, red) / (float)(S2n * Ln);
  for (int i = t; i < S2n * Ln; i += 256)
    outq[(size_t)b * S2n * Ln + i] = val + advb[i] - mean;
}

extern "C" void kernel_launch(void* const* d_in, const int* in_sizes, int n_in,
                              void* d_out, int out_size, void* d_ws, size_t ws_size,
                              hipStream_t stream)
{
  const float* states       = (const float*)d_in[0];
  const float* state_mask   = (const float*)d_in[1];
  const float* actions      = (const float*)d_in[2];
  const float* actions_mask = (const float*)d_in[3];
  const float* adj          = (const float*)d_in[4];
  const float* Wn  = (const float*)d_in[5];
  const float* bn  = (const float*)d_in[6];
  const float* Wu  = (const float*)d_in[7];
  const float* bu  = (const float*)d_in[8];
  const float* Wr  = (const float*)d_in[9];
  const float* br  = (const float*)d_in[10];
  const float* Wt  = (const float*)d_in[11];
  const float* bt  = (const float*)d_in[12];
  const float* Wa1 = (const float*)d_in[13];
  const float* ba1 = (const float*)d_in[14];
  const float* Wa2 = (const float*)d_in[15];
  const float* ba2 = (const float*)d_in[16];
  const float* Wv  = (const float*)d_in[17];
  const float* bvp = (const float*)d_in[18];
  const float* weight = (const float*)d_in[19];
  const float* bias   = (const float*)d_in[20];

  // Workspace layout (floats). ws_size = 256 MB.
  float* ws  = (float*)d_ws;
  float* h   = ws;                 // [B,S,H]
  float* p   = ws + (1 << 20);     // [B,S,H]
  float* a   = ws + 2 * (1 << 20); // [B,S,2H]
  float* zp  = ws + 4 * (1 << 20); // [B,S,H]  sigmoid(z)
  float* rp  = ws + 5 * (1 << 20); // [B,S,H]  sigmoid(r)*h
  float* qp  = a + (1 << 20);      // reuse after GGNN loop
  float* kp  = p;                  // written by last gemm_hp epilogue
  float* E   = zp;                 // reuse after loop
  float* sfb = rp;                 // reuse after loop
  float* adv = rp + 139264;
  // Transposed weights:
  float* WnT  = ws + 6 * (1 << 20);  // [128][128]
  float* WuT  = WnT + 16384;         // [256][128]
  float* WrT  = WuT + 32768;         // [256][128]
  float* WtT  = WrT + 32768;         // [256][128]
  float* Wa1T = WtT + 32768;         // [256][128] rows 0..127=TL,128..255=TR

  const int M = Bn * Sn;             // 8192
  const int lds128 = 16 * 128 * 4;

  transpose_all<<<dim3(8, 4, 5), 256, 0, stream>>>(
      Wn, Wu, Wr, Wt, Wa1, WnT, WuT, WrT, WtT, Wa1T);

  // p0 = states @ Wn^T + bn
  gemm_wt<<<M / 16, 256, lds128, stream>>>(states, WnT, bn, p, M, 128);

  for (int step = 0; step < 3; ++step) {
    const float* hin = (step == 0) ? states : h;
    adj_mm_sparse<<<dim3(Sn / 4, Bn), 256, 0, stream>>>(adj, p, hin, a);
    gemm_zr<<<M / 16, 256, 0, stream>>>(a, WuT, WrT, bu, br, hin, zp, rp);
    if (step < 2)
      gemm_hp<<<M / 16, 256, 0, stream>>>(p, rp, WtT, bt, zp, hin, h,
                                          WnT, bn, p);
    else
      gemm_hp<<<M / 16, 256, 0, stream>>>(p, rp, WtT, bt, zp, hin, h,
                                          Wa1T + 128 * 128, nullptr, kp);
  }

  // qp = actions @ Wa1TL
  gemm_wt<<<(Bn * S2n) / 16, 256, lds128, stream>>>(actions, Wa1T, nullptr, qp,
                                                    Bn * S2n, 128);

  scores_exp_v2<<<dim3(Sn / 32, Bn), 256, 0, stream>>>(qp, kp, ba1, Wa2, ba2,
                                                       actions_mask, state_mask, E);
  attn_sf<<<dim3(S2n, Bn), 128, 0, stream>>>(E, h, sfb);
  adv_kernel<<<dim3(S2n, Bn), 128, 0, stream>>>(actions, sfb, weight, bias, adv);
  final2_kernel<<<Bn, 256, 0, stream>>>(sfb, actions_mask, Wv, bvp, adv,
                                        (float*)d_out);
}

// Round 10
// 283.665 us; speedup vs baseline: 1.2222x; 1.2222x over previous
//
#include <hip/hip_runtime.h>
#include <math.h>

// Shapes (fixed by the reference)
constexpr int Bn  = 16;
constexpr int Sn  = 512;
constexpr int S2n = 64;
constexpr int Hn  = 128;
constexpr int Ln  = 3;

#define TID ((int)threadIdx.x)

__device__ inline float wave_reduce_sum(float v) {
#pragma unroll
  for (int off = 32; off > 0; off >>= 1) v += __shfl_xor(v, off, 64);
  return v;
}

__device__ inline float block_reduce_sum(float v, float* red) {
  v = wave_reduce_sum(v);
  int w  = TID >> 6;
  int nw = (int)blockDim.x >> 6;
  if ((TID & 63) == 0) red[w] = v;
  __syncthreads();
  float s = 0.f;
  for (int i = 0; i < nw; ++i) s += red[i];
  __syncthreads();
  return s;
}

__device__ inline float sigm(float x) { return 1.f / (1.f + expf(-x)); }

// Transposes: z=0: WtRT[k][n] = Wt[n][128+k] (K=128); z=1: Wa1T (K=256).
__global__ __launch_bounds__(256) void transpose2(
    const float* __restrict__ Wt, const float* __restrict__ Wa1,
    float* __restrict__ WtRT, float* __restrict__ Wa1T)
{
  const float* src; float* dst; int K, woff;
  if (blockIdx.z == 0) { src = Wt;  dst = WtRT; K = 128; woff = 128; }
  else                 { src = Wa1; dst = Wa1T; K = 256; woff = 0; }
  int k0 = blockIdx.x * 32;
  if (k0 >= K) return;
  int n0 = blockIdx.y * 32;
  __shared__ float t[32][33];
  int tx = TID & 31, ty = TID >> 5;
#pragma unroll
  for (int i = 0; i < 32; i += 8)
    t[ty + i][tx] = src[(size_t)(n0 + ty + i) * 256 + woff + k0 + tx];
  __syncthreads();
#pragma unroll
  for (int i = 0; i < 32; i += 8)
    dst[(size_t)(k0 + ty + i) * 128 + n0 + tx] = t[tx][ty + i];
}

// Combined matrices: GT[k][n] = sum_c Wn[c][k]*W[n][c] (+ W[n][128+k] for u,r)
// cvec[n] = sum_c bn[c]*W[n][c].   mat: 0=Wu->Gu/cu, 1=Wr->Gr/cr, 2=Wt->Gt/ct.
__global__ __launch_bounds__(128) void combine_weights(
    const float* __restrict__ Wn, const float* __restrict__ Wu,
    const float* __restrict__ Wr, const float* __restrict__ Wt,
    const float* __restrict__ bn,
    float* __restrict__ GuT, float* __restrict__ GrT, float* __restrict__ GtT,
    float* __restrict__ cu, float* __restrict__ cr, float* __restrict__ ct)
{
  int n = blockIdx.x, mat = blockIdx.y;
  const float* W; float* GT; float* cv;
  if (mat == 0)      { W = Wu; GT = GuT; cv = cu; }
  else if (mat == 1) { W = Wr; GT = GrT; cv = cr; }
  else               { W = Wt; GT = GtT; cv = ct; }
  __shared__ float Ws[128], bns[128];
  __shared__ float red[2];
  int k = TID;
  Ws[k]  = W[(size_t)n * 256 + k];
  bns[k] = bn[k];
  __syncthreads();
  float acc = 0.f;
#pragma unroll 4
  for (int c = 0; c < 128; ++c)
    acc = fmaf(Wn[(size_t)c * 128 + k], Ws[c], acc);
  if (mat < 2) acc += W[(size_t)n * 256 + 128 + k];
  GT[(size_t)k * 128 + n] = acc;
  float pv = bns[k] * Ws[k];
  pv = wave_reduce_sum(pv);
  if ((k & 63) == 0) red[k >> 6] = pv;
  __syncthreads();
  if (k == 0) cv[n] = red[0] + red[1];
}

// deg[row] = sum_j adj[row][j]   (row = b*Sn + i)
__global__ __launch_bounds__(256) void deg_kernel(
    const float* __restrict__ adj, float* __restrict__ deg)
{
  int wid = TID >> 6, lane = TID & 63;
  int row = blockIdx.x * 4 + wid;
  const float* ar = adj + (size_t)row * Sn;
  float4 a = ((const float4*)ar)[lane];
  float4 b = ((const float4*)ar)[64 + lane];
  float s = a.x + a.y + a.z + a.w + b.x + b.y + b.z + b.w;
  s = wave_reduce_sum(s);
  if (lane == 0) deg[row] = s;
}

// g[row][0:128]=h@GuT, [128:256]=h@GrT, [256:384]=h@GtT+ct.  K=128.
__global__ __launch_bounds__(256) void gemm_g(
    const float* __restrict__ h,
    const float* __restrict__ GuT, const float* __restrict__ GrT,
    const float* __restrict__ GtT, const float* __restrict__ ctv,
    float* __restrict__ g)
{
  __shared__ float Xs[16 * 128];
  int r0 = blockIdx.x * 16;
  const float* xsrc = h + (size_t)r0 * 128;
  for (int i = TID; i < 512; i += 256)
    ((float4*)Xs)[i] = ((const float4*)xsrc)[i];
  __syncthreads();

  int cg = (TID & 63) * 2;
  int rb = (TID >> 6) * 4;
  float aU[4][2] = {}, aR[4][2] = {}, aT[4][2] = {};

#pragma unroll 2
  for (int k = 0; k < 128; k += 4) {
    const float* pu = GuT + (size_t)k * 128 + cg;
    const float* pr = GrT + (size_t)k * 128 + cg;
    const float* pt = GtT + (size_t)k * 128 + cg;
    float2 u0 = *(const float2*)(pu);
    float2 u1 = *(const float2*)(pu + 128);
    float2 u2 = *(const float2*)(pu + 256);
    float2 u3 = *(const float2*)(pu + 384);
    float2 q0 = *(const float2*)(pr);
    float2 q1 = *(const float2*)(pr + 128);
    float2 q2 = *(const float2*)(pr + 256);
    float2 q3 = *(const float2*)(pr + 384);
    float2 t0 = *(const float2*)(pt);
    float2 t1 = *(const float2*)(pt + 128);
    float2 t2 = *(const float2*)(pt + 256);
    float2 t3 = *(const float2*)(pt + 384);
#pragma unroll
    for (int i = 0; i < 4; ++i) {
      float4 x = *(const float4*)&Xs[(rb + i) * 128 + k];
      aU[i][0] = fmaf(x.x, u0.x, aU[i][0]);
      aU[i][0] = fmaf(x.y, u1.x, aU[i][0]);
      aU[i][0] = fmaf(x.z, u2.x, aU[i][0]);
      aU[i][0] = fmaf(x.w, u3.x, aU[i][0]);
      aU[i][1] = fmaf(x.x, u0.y, aU[i][1]);
      aU[i][1] = fmaf(x.y, u1.y, aU[i][1]);
      aU[i][1] = fmaf(x.z, u2.y, aU[i][1]);
      aU[i][1] = fmaf(x.w, u3.y, aU[i][1]);
      aR[i][0] = fmaf(x.x, q0.x, aR[i][0]);
      aR[i][0] = fmaf(x.y, q1.x, aR[i][0]);
      aR[i][0] = fmaf(x.z, q2.x, aR[i][0]);
      aR[i][0] = fmaf(x.w, q3.x, aR[i][0]);
      aR[i][1] = fmaf(x.x, q0.y, aR[i][1]);
      aR[i][1] = fmaf(x.y, q1.y, aR[i][1]);
      aR[i][1] = fmaf(x.z, q2.y, aR[i][1]);
      aR[i][1] = fmaf(x.w, q3.y, aR[i][1]);
      aT[i][0] = fmaf(x.x, t0.x, aT[i][0]);
      aT[i][0] = fmaf(x.y, t1.x, aT[i][0]);
      aT[i][0] = fmaf(x.z, t2.x, aT[i][0]);
      aT[i][0] = fmaf(x.w, t3.x, aT[i][0]);
      aT[i][1] = fmaf(x.x, t0.y, aT[i][1]);
      aT[i][1] = fmaf(x.y, t1.y, aT[i][1]);
      aT[i][1] = fmaf(x.z, t2.y, aT[i][1]);
      aT[i][1] = fmaf(x.w, t3.y, aT[i][1]);
    }
  }

  float2 ct2 = *(const float2*)(ctv + cg);
#pragma unroll
  for (int i = 0; i < 4; ++i) {
    float* base = g + (size_t)(r0 + rb + i) * 384;
    float2 vu = {aU[i][0], aU[i][1]};
    float2 vr = {aR[i][0], aR[i][1]};
    float2 vt = {aT[i][0] + ct2.x, aT[i][1] + ct2.y};
    *(float2*)(base + cg)       = vu;
    *(float2*)(base + 128 + cg) = vr;
    *(float2*)(base + 256 + cg) = vt;
  }
}

// Sparse adjacency over [gu|gr] + gate epilogue:
// z = sigm(adj@gu + deg*cu + bu); rh = sigm(adj@gr + deg*cr + br) * h.
__global__ __launch_bounds__(256) void adj_gate(
    const float* __restrict__ adj, const float* __restrict__ g,
    const float* __restrict__ h, const float* __restrict__ deg,
    const float* __restrict__ cu, const float* __restrict__ cr,
    const float* __restrict__ bu, const float* __restrict__ br,
    float* __restrict__ z, float* __restrict__ rh)
{
  int wid = TID >> 6, lane = TID & 63;
  int b = blockIdx.y;
  int i = blockIdx.x * 4 + wid;

  int c = (lane < 32) ? 4 * lane : 128 + 4 * (lane - 32);
  const float* gb = g + (size_t)b * Sn * 384 + c;
  const float* arow = adj + ((size_t)b * Sn + i) * Sn;

  float4 acc = {0.f, 0.f, 0.f, 0.f};
  for (int j0 = 0; j0 < Sn; j0 += 64) {
    float av = arow[j0 + lane];
    unsigned long long mask = __ballot(av != 0.f);
    while (mask) {
      int jj = __ffsll((unsigned long long)mask) - 1;
      mask &= mask - 1;
      float w = __shfl(av, jj, 64);
      float4 x = *(const float4*)(gb + (size_t)(j0 + jj) * 384);
      acc.x = fmaf(w, x.x, acc.x);
      acc.y = fmaf(w, x.y, acc.y);
      acc.z = fmaf(w, x.z, acc.z);
      acc.w = fmaf(w, x.w, acc.w);
    }
  }

  size_t row = (size_t)b * Sn + i;
  float d = deg[row];
  int cc = (lane < 32) ? 4 * lane : 4 * (lane - 32);
  const float* cvp = (lane < 32) ? cu : cr;
  const float* bvp = (lane < 32) ? bu : br;
  float4 cv = *(const float4*)(cvp + cc);
  float4 bv = *(const float4*)(bvp + cc);
  float4 sg;
  sg.x = sigm(acc.x + d * cv.x + bv.x);
  sg.y = sigm(acc.y + d * cv.y + bv.y);
  sg.z = sigm(acc.z + d * cv.z + bv.z);
  sg.w = sigm(acc.w + d * cv.w + bv.w);
  if (lane < 32) {
    *(float4*)(z + row * 128 + cc) = sg;
  } else {
    float4 hv = *(const float4*)(h + row * 128 + cc);
    sg.x *= hv.x; sg.y *= hv.y; sg.z *= hv.z; sg.w *= hv.w;
    *(float4*)(rh + row * 128 + cc) = sg;
  }
}

// h_new = h_in + z*(tanh(rh@WtRT + g_t + bt) - h_in); optional epilogue
// e_out = h_new @ WeT (row-local; used for kp on the last step).
__global__ __launch_bounds__(256) void gemm_hh(
    const float* __restrict__ rh, const float* __restrict__ g,
    const float* __restrict__ WtRT, const float* __restrict__ bt,
    const float* __restrict__ z, const float* __restrict__ h_in,
    float* __restrict__ h_out,
    const float* __restrict__ WeT, float* __restrict__ e_out)
{
  __shared__ float Xs[16 * 128];
  int r0 = blockIdx.x * 16;
  const float* xsrc = rh + (size_t)r0 * 128;
  for (int i = TID; i < 512; i += 256)
    ((float4*)Xs)[i] = ((const float4*)xsrc)[i];
  __syncthreads();

  int cg = (TID & 63) * 2;
  int rb = (TID >> 6) * 4;
  float acc[4][2] = {};

#pragma unroll 4
  for (int k = 0; k < 128; k += 4) {
    const float* wk = WtRT + (size_t)k * 128 + cg;
    float2 w0 = *(const float2*)(wk);
    float2 w1 = *(const float2*)(wk + 128);
    float2 w2 = *(const float2*)(wk + 256);
    float2 w3 = *(const float2*)(wk + 384);
#pragma unroll
    for (int i = 0; i < 4; ++i) {
      float4 x = *(const float4*)&Xs[(rb + i) * 128 + k];
      acc[i][0] = fmaf(x.x, w0.x, acc[i][0]);
      acc[i][0] = fmaf(x.y, w1.x, acc[i][0]);
      acc[i][0] = fmaf(x.z, w2.x, acc[i][0]);
      acc[i][0] = fmaf(x.w, w3.x, acc[i][0]);
      acc[i][1] = fmaf(x.x, w0.y, acc[i][1]);
      acc[i][1] = fmaf(x.y, w1.y, acc[i][1]);
      acc[i][1] = fmaf(x.z, w2.y, acc[i][1]);
      acc[i][1] = fmaf(x.w, w3.y, acc[i][1]);
    }
  }

  float2 btv = *(const float2*)(bt + cg);
  float hn[4][2];
#pragma unroll
  for (int i = 0; i < 4; ++i) {
    size_t row = r0 + rb + i;
    float2 gt = *(const float2*)(g + row * 384 + 256 + cg);
    float2 hv = *(const float2*)(h_in + row * 128 + cg);
    float2 zv = *(const float2*)(z + row * 128 + cg);
    float t0 = tanhf(acc[i][0] + gt.x + btv.x);
    float t1 = tanhf(acc[i][1] + gt.y + btv.y);
    hn[i][0] = hv.x + zv.x * (t0 - hv.x);
    hn[i][1] = hv.y + zv.y * (t1 - hv.y);
    float2 o = {hn[i][0], hn[i][1]};
    *(float2*)(h_out + row * 128 + cg) = o;
  }

  if (WeT) {
    __syncthreads();
#pragma unroll
    for (int i = 0; i < 4; ++i) {
      Xs[(rb + i) * 128 + cg]     = hn[i][0];
      Xs[(rb + i) * 128 + cg + 1] = hn[i][1];
    }
    __syncthreads();
    float acc2[4][2] = {};
#pragma unroll 4
    for (int k = 0; k < 128; k += 4) {
      const float* wk = WeT + (size_t)k * 128 + cg;
      float2 w0 = *(const float2*)(wk);
      float2 w1 = *(const float2*)(wk + 128);
      float2 w2 = *(const float2*)(wk + 256);
      float2 w3 = *(const float2*)(wk + 384);
#pragma unroll
      for (int i = 0; i < 4; ++i) {
        float4 x = *(const float4*)&Xs[(rb + i) * 128 + k];
        acc2[i][0] = fmaf(x.x, w0.x, acc2[i][0]);
        acc2[i][0] = fmaf(x.y, w1.x, acc2[i][0]);
        acc2[i][0] = fmaf(x.z, w2.x, acc2[i][0]);
        acc2[i][0] = fmaf(x.w, w3.x, acc2[i][0]);
        acc2[i][1] = fmaf(x.x, w0.y, acc2[i][1]);
        acc2[i][1] = fmaf(x.y, w1.y, acc2[i][1]);
        acc2[i][1] = fmaf(x.z, w2.y, acc2[i][1]);
        acc2[i][1] = fmaf(x.w, w3.y, acc2[i][1]);
      }
    }
#pragma unroll
    for (int i = 0; i < 4; ++i) {
      float2 v = {acc2[i][0], acc2[i][1]};
      *(float2*)(e_out + (size_t)(r0 + rb + i) * 128 + cg) = v;
    }
  }
}

// Y[M,128] = X[M,K] @ WT[K,128] (+bias). Used for qp.
__global__ __launch_bounds__(256) void gemm_wt(
    const float* __restrict__ X, const float* __restrict__ WT,
    const float* __restrict__ bias, float* __restrict__ Y,
    int M, int K)
{
  extern __shared__ float Xs[];
  int r0 = blockIdx.x * 16;
  const float* xsrc = X + (size_t)r0 * K;
  int tot4 = (16 * K) >> 2;
  for (int i = TID; i < tot4; i += 256)
    ((float4*)Xs)[i] = ((const float4*)xsrc)[i];
  __syncthreads();

  int cg = (TID & 63) * 2;
  int rb = (TID >> 6) * 4;
  float acc[4][2] = {};

#pragma unroll 4
  for (int k = 0; k < K; k += 4) {
    const float* wk = WT + (size_t)k * 128 + cg;
    float2 w0 = *(const float2*)(wk);
    float2 w1 = *(const float2*)(wk + 128);
    float2 w2 = *(const float2*)(wk + 256);
    float2 w3 = *(const float2*)(wk + 384);
#pragma unroll
    for (int i = 0; i < 4; ++i) {
      float4 x = *(const float4*)&Xs[(rb + i) * K + k];
      acc[i][0] = fmaf(x.x, w0.x, acc[i][0]);
      acc[i][0] = fmaf(x.y, w1.x, acc[i][0]);
      acc[i][0] = fmaf(x.z, w2.x, acc[i][0]);
      acc[i][0] = fmaf(x.w, w3.x, acc[i][0]);
      acc[i][1] = fmaf(x.x, w0.y, acc[i][1]);
      acc[i][1] = fmaf(x.y, w1.y, acc[i][1]);
      acc[i][1] = fmaf(x.z, w2.y, acc[i][1]);
      acc[i][1] = fmaf(x.w, w3.y, acc[i][1]);
    }
  }

  float2 bv = {0.f, 0.f};
  if (bias) bv = *(const float2*)(bias + cg);
#pragma unroll
  for (int i = 0; i < 4; ++i) {
    float2 v = {acc[i][0] + bv.x, acc[i][1] + bv.y};
    *(float2*)(Y + (size_t)(r0 + rb + i) * 128 + cg) = v;
  }
}

// E[b,q,k] = mask ? exp(relu(Wa2 . relu(qp[b,q]+kp[b,k]+ba1) + ba2)) : 0
__global__ __launch_bounds__(256) void scores_exp_v2(
    const float* __restrict__ qp, const float* __restrict__ kp,
    const float* __restrict__ ba1, const float* __restrict__ Wa2,
    const float* __restrict__ ba2, const float* __restrict__ am,
    const float* __restrict__ sm, float* __restrict__ E)
{
  constexpr int KT = 32;
  __shared__ float qs[64][132];
  __shared__ float ks[KT][132];
  __shared__ float w2s[128];
  __shared__ float es[64][33];

  int b = blockIdx.y, kt = blockIdx.x * KT;

  const float* qsrc = qp + (size_t)b * S2n * Hn;
  for (int f = TID; f < 64 * 32; f += 256) {
    int q = f >> 5, g = f & 31;
    float4 v  = ((const float4*)qsrc)[f];
    float4 bb = ((const float4*)ba1)[g];
    v.x += bb.x; v.y += bb.y; v.z += bb.z; v.w += bb.w;
    *(float4*)&qs[q][4 * g] = v;
  }
  const float* ksrc = kp + ((size_t)b * Sn + kt) * Hn;
  for (int f = TID; f < KT * 32; f += 256) {
    int k = f >> 5, g = f & 31;
    *(float4*)&ks[k][4 * g] = ((const float4*)ksrc)[f];
  }
  if (TID < 128) w2s[TID] = Wa2[TID];
  __syncthreads();

  const int q0 = (TID & 15) * 4;
  const int k0 = (TID >> 4) * 2;
  float acc[4][2] = {};

#pragma unroll 4
  for (int h = 0; h < 128; ++h) {
    float w  = w2s[h];
    float kv0 = ks[k0][h], kv1 = ks[k0 + 1][h];
#pragma unroll
    for (int i = 0; i < 4; ++i) {
      float qv = qs[q0 + i][h];
      acc[i][0] = fmaf(fmaxf(qv + kv0, 0.f), w, acc[i][0]);
      acc[i][1] = fmaf(fmaxf(qv + kv1, 0.f), w, acc[i][1]);
    }
  }

  float b2 = ba2[0];
#pragma unroll
  for (int i = 0; i < 4; ++i) {
    float amq = am[b * S2n + q0 + i];
#pragma unroll
    for (int j = 0; j < 2; ++j) {
      float m = amq * sm[b * Sn + kt + k0 + j];
      float s = fmaxf(acc[i][j] + b2, 0.f);
      es[q0 + i][k0 + j] = (m > 0.f) ? expf(s) : 0.f;
    }
  }
  __syncthreads();

  float* Eb = E + ((size_t)b * S2n) * Sn + kt;
  for (int f = TID; f < 64 * KT; f += 256) {
    int q = f >> 5, kin = f & 31;
    Eb[(size_t)q * Sn + kin] = es[q][kin];
  }
}

// sf[b,q,:] = (1/max(sum_k E,2e-15)) * sum_k E[b,q,k]*out[b,k,:]
__global__ __launch_bounds__(128) void attn_sf(
    const float* __restrict__ E, const float* __restrict__ out,
    float* __restrict__ sf)
{
  __shared__ float Es[512];
  __shared__ float red[2];
  int b = blockIdx.y, q = blockIdx.x, t = TID;
  const float* Erow = E + ((size_t)b * S2n + q) * Sn;
  for (int i = t; i < Sn; i += 128) Es[i] = Erow[i];
  __syncthreads();
  float part = Es[t] + Es[t + 128] + Es[t + 256] + Es[t + 384];
  part = wave_reduce_sum(part);
  if ((t & 63) == 0) red[t >> 6] = part;
  __syncthreads();
  float scale = 1.f / fmaxf(red[0] + red[1], 2e-15f);

  const float* ob = out + (size_t)b * Sn * Hn + t;
  float acc = 0.f;
#pragma unroll 8
  for (int k = 0; k < Sn; ++k) acc = fmaf(Es[k], ob[(size_t)k * Hn], acc);
  sf[((size_t)b * S2n + q) * Hn + t] = acc * scale;
}

// adv[b,s,l] = sum_h actions[b,s,h] * (weight[l] @ sf[b,s])_h + bias[l]
__global__ __launch_bounds__(128) void adv_kernel(
    const float* __restrict__ actions, const float* __restrict__ sf,
    const float* __restrict__ weight, const float* __restrict__ bias,
    float* __restrict__ adv)
{
  __shared__ float acts[128], sfs[128];
  __shared__ float red[2];
  int b = blockIdx.y, s = blockIdx.x, t = TID;
  size_t row = (size_t)b * S2n + s;
  acts[t] = actions[row * Hn + t];
  sfs[t]  = sf[row * Hn + t];
  __syncthreads();
  for (int l = 0; l < Ln; ++l) {
    const float* wr = weight + ((size_t)l * Hn + t) * Hn;
    float tmp = 0.f;
#pragma unroll 4
    for (int k = 0; k < Hn; k += 4) {
      float4 wv = *(const float4*)(wr + k);
      tmp = fmaf(wv.x, sfs[k],     tmp);
      tmp = fmaf(wv.y, sfs[k + 1], tmp);
      tmp = fmaf(wv.z, sfs[k + 2], tmp);
      tmp = fmaf(wv.w, sfs[k + 3], tmp);
    }
    float pa  = acts[t] * tmp;
    float tot = block_reduce_sum(pa, red);
    if (t == 0) adv[row * Ln + l] = tot + bias[l];
  }
}

// Fused: sem = mean_q sf ; val = Wv.sem+bv ; q = val + adv - mean(adv)
__global__ __launch_bounds__(256) void final2_kernel(
    const float* __restrict__ sf, const float* __restrict__ am,
    const float* __restrict__ Wv, const float* __restrict__ bv,
    const float* __restrict__ adv, float* __restrict__ outq)
{
  __shared__ float red[4];
  int b = blockIdx.x, t = TID;
  float num = 0.f;
  for (int i = 0; i < S2n; ++i) num += am[b * S2n + i];
  float pv = 0.f;
  if (t < Hn) {
    float s = 0.f;
    const float* sb = sf + (size_t)b * S2n * Hn + t;
    for (int q = 0; q < S2n; ++q) s += sb[(size_t)q * Hn];
    pv = Wv[t] * (s / num);
  }
  float val = block_reduce_sum(pv, red) + bv[0];
  const float* advb = adv + (size_t)b * S2n * Ln;
  float pa   = (t < S2n * Ln) ? advb[t] : 0.f;
  float mean = block_reduce_sum(pa, red) / (float)(S2n * Ln);
  for (int i = t; i < S2n * Ln; i += 256)
    outq[(size_t)b * S2n * Ln + i] = val + advb[i] - mean;
}

extern "C" void kernel_launch(void* const* d_in, const int* in_sizes, int n_in,
                              void* d_out, int out_size, void* d_ws, size_t ws_size,
                              hipStream_t stream)
{
  const float* states       = (const float*)d_in[0];
  const float* state_mask   = (const float*)d_in[1];
  const float* actions      = (const float*)d_in[2];
  const float* actions_mask = (const float*)d_in[3];
  const float* adj          = (const float*)d_in[4];
  const float* Wn  = (const float*)d_in[5];
  const float* bn  = (const float*)d_in[6];
  const float* Wu  = (const float*)d_in[7];
  const float* bu  = (const float*)d_in[8];
  const float* Wr  = (const float*)d_in[9];
  const float* br  = (const float*)d_in[10];
  const float* Wt  = (const float*)d_in[11];
  const float* bt  = (const float*)d_in[12];
  const float* Wa1 = (const float*)d_in[13];
  const float* ba1 = (const float*)d_in[14];
  const float* Wa2 = (const float*)d_in[15];
  const float* ba2 = (const float*)d_in[16];
  const float* Wv  = (const float*)d_in[17];
  const float* bvp = (const float*)d_in[18];
  const float* weight = (const float*)d_in[19];
  const float* bias   = (const float*)d_in[20];

  // Workspace layout (floats).
  float* ws   = (float*)d_ws;
  float* h    = ws;                   // [8192][128]
  float* g    = ws + (1 << 20);       // [8192][384] (3M floats)
  float* zp   = ws + 4 * (1 << 20);   // [8192][128]
  float* rh   = ws + 5 * (1 << 20);   // [8192][128]
  float* kp   = ws + 6 * (1 << 20);   // [8192][128]
  float* qp   = ws + 7 * (1 << 20);   // [1024][128]
  float* E    = ws + 8 * (1 << 20);   // [16][64][512]
  float* sfb  = ws + 9 * (1 << 20);   // [16][64][128]
  float* adv  = sfb + 262144;         // [16][64][3]
  float* deg  = ws + 10 * (1 << 20);  // [8192]
  float* WtRT = deg + 16384;          // [128][128]
  float* Wa1T = WtRT + 16384;         // [256][128]
  float* GuT  = Wa1T + 32768;         // [128][128]
  float* GrT  = GuT + 16384;          // [128][128]
  float* GtT  = GrT + 16384;          // [128][128]
  float* cu   = GtT + 16384;          // [128]
  float* cr   = cu + 128;             // [128]
  float* ct   = cr + 128;             // [128]

  const int M = Bn * Sn;              // 8192
  const int lds128 = 16 * 128 * 4;

  transpose2<<<dim3(8, 4, 2), 256, 0, stream>>>(Wt, Wa1, WtRT, Wa1T);
  combine_weights<<<dim3(128, 3), 128, 0, stream>>>(Wn, Wu, Wr, Wt, bn,
                                                    GuT, GrT, GtT, cu, cr, ct);
  deg_kernel<<<M / 4, 256, 0, stream>>>(adj, deg);

  for (int step = 0; step < 3; ++step) {
    const float* hin = (step == 0) ? states : h;
    gemm_g<<<M / 16, 256, 0, stream>>>(hin, GuT, GrT, GtT, ct, g);
    adj_gate<<<dim3(Sn / 4, Bn), 256, 0, stream>>>(adj, g, hin, deg,
                                                   cu, cr, bu, br, zp, rh);
    gemm_hh<<<M / 16, 256, 0, stream>>>(rh, g, WtRT, bt, zp, hin, h,
                                        step == 2 ? Wa1T + 128 * 128 : nullptr,
                                        kp);
  }

  // qp = actions @ Wa1TL
  gemm_wt<<<(Bn * S2n) / 16, 256, lds128, stream>>>(actions, Wa1T, nullptr, qp,
                                                    Bn * S2n, 128);

  scores_exp_v2<<<dim3(Sn / 32, Bn), 256, 0, stream>>>(qp, kp, ba1, Wa2, ba2,
                                                       actions_mask, state_mask, E);
  attn_sf<<<dim3(S2n, Bn), 128, 0, stream>>>(E, h, sfb);
  adv_kernel<<<dim3(S2n, Bn), 128, 0, stream>>>(actions, sfb, weight, bias, adv);
  final2_kernel<<<Bn, 256, 0, stream>>>(sfb, actions_mask, Wv, bvp, adv,
                                        (float*)d_out);
}